// Round 3
// baseline (308.141 us; speedup 1.0000x reference)
//
#include <hip/hip_runtime.h>
#include <hip/hip_bf16.h>
#include <math.h>

// Problem constants: N=768, D=32, C=10, H=256, INPUT_DIM=149.
// Pairs P = N*N = 589824. MLP: [P,149]@[149,256] relu @[256,256] relu @[256,1].
//
// Decomposition: feat@W1 + b1 = |zi-zj|@W1[64:96] + (zi*zj)@W1[96:128]
//                              + R[i] + C[j]
// where R[i] = z[i]@W1[0:32] + p[i]@W1[128:138]
//       C[j] = z[j]@W1[32:64] + p[j]@W1[138:148] + b1 + hom*W1[148]
// R/C are injected into the layer-1 MFMA via one-hot K-columns (fp16 + fp16
// residual for near-exact base add). Effective K1 = 96 (3 MFMA k-steps).

typedef _Float16 f16x8 __attribute__((ext_vector_type(8)));
typedef float f32x4 __attribute__((ext_vector_type(4)));

#define MFMA16(a, b, c) __builtin_amdgcn_mfma_f32_16x16x32_f16(a, b, c, 0, 0, 0)

#define NN 768
#define HH 256

// ---------------- prep kernels ----------------

__global__ void prep_rc(const float* __restrict__ z, const float* __restrict__ lp,
                        const float* __restrict__ hom, const float* __restrict__ W1,
                        const float* __restrict__ b1,
                        _Float16* __restrict__ Rh, _Float16* __restrict__ Ch,
                        _Float16* __restrict__ R2h, _Float16* __restrict__ C2h) {
  int i = blockIdx.x;       // 0..767
  int n = threadIdx.x;      // 0..255
  float r = 0.f, c = 0.f;
  #pragma unroll 8
  for (int d = 0; d < 32; ++d) {
    float zv = z[i * 32 + d];
    r += zv * W1[d * HH + n];
    c += zv * W1[(32 + d) * HH + n];
  }
  #pragma unroll
  for (int k = 0; k < 10; ++k) {
    float pv = lp[i * 10 + k];
    r += pv * W1[(128 + k) * HH + n];
    c += pv * W1[(138 + k) * HH + n];
  }
  c += b1[n] + hom[0] * W1[148 * HH + n];
  _Float16 rh = (_Float16)r, ch = (_Float16)c;
  Rh[i * HH + n] = rh;
  Ch[i * HH + n] = ch;
  R2h[i * HH + n] = (_Float16)(r - (float)rh);
  C2h[i * HH + n] = (_Float16)(c - (float)ch);
}

// Wm[n][kk] (kk<32 -> W1 row 64+kk (abs), kk>=32 -> W1 row 96+kk-32 (prod)), f16.
// W2t[n][k] = W2[k][n], f16.
__global__ void prep_w(const float* __restrict__ W1, const float* __restrict__ W2,
                       _Float16* __restrict__ Wm, _Float16* __restrict__ W2t) {
  int idx = blockIdx.x * 256 + threadIdx.x;  // grid 320 -> 81920 = 16384 + 65536
  if (idx < 256 * 64) {
    int n = idx >> 6, kk = idx & 63;
    float v = (kk < 32) ? W1[(64 + kk) * HH + n] : W1[(96 + (kk - 32)) * HH + n];
    Wm[n * 64 + kk] = (_Float16)v;
  } else {
    int q = idx - 256 * 64;
    int n = q >> 8, k = q & 255;
    W2t[n * 256 + k] = (_Float16)W2[k * 256 + n];
  }
}

// ---------------- fused MLP ----------------
// grid (96,96), 256 threads (4 waves). Block = 64 pairs (8 i x 8 j), full H=256.
// Wave w handles pairs [16w,16w+16). LDS: h1 (32KB, swizzled) + wbuf (32KB).

__global__ __launch_bounds__(256, 2) void fused_mlp(
    const float* __restrict__ z,
    const _Float16* __restrict__ Rh, const _Float16* __restrict__ Ch,
    const _Float16* __restrict__ R2h, const _Float16* __restrict__ C2h,
    const _Float16* __restrict__ Wm, const _Float16* __restrict__ W2t,
    const float* __restrict__ b2, const float* __restrict__ W3,
    const float* __restrict__ b3, float* __restrict__ out) {
  __shared__ __align__(16) unsigned char lds[65536];
  unsigned char* h1raw = lds;           // [64 rows][512B] XOR-swizzled
  unsigned char* wbuf = lds + 32768;    // [256 rows][128B] XOR-swizzled

  const int tid = threadIdx.x;
  const int wid = tid >> 6;
  const int l = tid & 63;
  const int lr = l & 15;   // A-row / B-col / D-col lane index
  const int lg = l >> 4;   // k-group
  const int bi = blockIdx.x, bj = blockIdx.y;

  // ---- stage Wm (layer-1 B panel, 32KB) into wbuf ----
  #pragma unroll
  for (int s = 0; s < 8; ++s) {
    int q = tid + 256 * s;
    int n = q >> 3, c = q & 7;
    const int4 v = *(const int4*)((const char*)Wm + n * 128 + c * 16);
    *(int4*)(wbuf + n * 128 + ((c * 16) ^ ((n & 7) << 4))) = v;
  }

  // ---- per-lane preloads ----
  float b2v[16], w3v[16];
  #pragma unroll
  for (int nf = 0; nf < 16; ++nf) {
    b2v[nf] = b2[nf * 16 + lr];
    w3v[nf] = W3[nf * 16 + lr];
  }
  const float b3v = b3[0];

  // ---- build layer-1 A-fragments in registers ----
  const int p = wid * 16 + lr;          // pair within block
  const int il = p >> 3, jl = p & 7;
  const int gi = bi * 8 + il, gj = bj * 8 + jl;
  f16x8 a0, a1, a2;
  {
    const float* zi = z + gi * 32 + lg * 8;
    const float* zj = z + gj * 32 + lg * 8;
    #pragma unroll
    for (int t = 0; t < 8; ++t) {
      float x = zi[t], y = zj[t];
      a0[t] = (_Float16)fabsf(x - y);
      a1[t] = (_Float16)(x * y);
    }
    #pragma unroll
    for (int t = 0; t < 8; ++t) {
      int kk = lg * 8 + t;  // 0..31 within k-step 2
      float v;
      if (kk < 8)       v = (kk == il)      ? 1.f : 0.f;  // R one-hot
      else if (kk < 16) v = (kk - 8 == jl)  ? 1.f : 0.f;  // C one-hot
      else if (kk < 24) v = (kk - 16 == il) ? 1.f : 0.f;  // R residual
      else              v = (kk - 24 == jl) ? 1.f : 0.f;  // C residual
      a2[t] = (_Float16)v;
    }
  }
  __syncthreads();  // Wm staged

  // ---- layer 1: [64x96] @ [96x256] ----
  f32x4 acc1[16];
  #pragma unroll
  for (int nf = 0; nf < 16; ++nf) acc1[nf] = (f32x4){0.f, 0.f, 0.f, 0.f};

  #pragma unroll
  for (int ks = 0; ks < 2; ++ks) {
    f16x8 a = ks ? a1 : a0;
    #pragma unroll
    for (int nf = 0; nf < 16; ++nf) {
      int n = nf * 16 + lr;
      f16x8 b = *(const f16x8*)(wbuf + n * 128 + ((ks * 64 + lg * 16) ^ ((n & 7) << 4)));
      acc1[nf] = MFMA16(a, b, acc1[nf]);
    }
  }
  {  // k-step 2: one-hot R/C injection (B from global, L2-hot)
    #pragma unroll
    for (int nf = 0; nf < 16; ++nf) {
      int n = nf * 16 + lr;
      const _Float16* src = (lg == 0) ? (Rh + (bi * 8) * HH + n)
                          : (lg == 1) ? (Ch + (bj * 8) * HH + n)
                          : (lg == 2) ? (R2h + (bi * 8) * HH + n)
                                      : (C2h + (bj * 8) * HH + n);
      f16x8 b;
      #pragma unroll
      for (int t = 0; t < 8; ++t) b[t] = src[t * HH];
      acc1[nf] = MFMA16(a2, b, acc1[nf]);
    }
  }

  // ---- relu + pack h1 to LDS (f16, swizzled) ----
  #pragma unroll
  for (int nf = 0; nf < 16; ++nf) {
    #pragma unroll
    for (int r = 0; r < 4; ++r) {
      int row = wid * 16 + lg * 4 + r;   // pair (D layout: row=(l>>4)*4+reg)
      int col = nf * 16 + lr;            // hidden col (D layout: col=l&15)
      float v = acc1[nf][r];
      v = v > 0.f ? v : 0.f;
      *(_Float16*)(h1raw + row * 512 + ((col * 2) ^ ((row & 7) << 4))) = (_Float16)v;
    }
  }

  // ---- layer 2: [64x256] @ [256x256], W2t staged in 64-k tiles ----
  f32x4 acc2[16];
  #pragma unroll
  for (int nf = 0; nf < 16; ++nf) acc2[nf] = (f32x4){0.f, 0.f, 0.f, 0.f};

  for (int kt = 0; kt < 4; ++kt) {
    __syncthreads();  // h1 ready (kt=0) / previous tile consumed
    // stage full 64-k slice: 256 rows x 128 bytes = 32KB = 2048 x 16B chunks
    #pragma unroll
    for (int s = 0; s < 8; ++s) {
      int q = tid + 256 * s;
      int n = q >> 3, c = q & 7;
      const int4 v = *(const int4*)((const char*)W2t + n * 512 + kt * 128 + c * 16);
      *(int4*)(wbuf + n * 128 + ((c * 16) ^ ((n & 7) << 4))) = v;
    }
    __syncthreads();
    #pragma unroll
    for (int ks = 0; ks < 2; ++ks) {
      int row = wid * 16 + lr;
      int kb = kt * 128 + ks * 64 + lg * 16;
      f16x8 a = *(const f16x8*)(h1raw + row * 512 + (kb ^ ((row & 7) << 4)));
      #pragma unroll
      for (int nf = 0; nf < 16; ++nf) {
        int n = nf * 16 + lr;
        f16x8 b = *(const f16x8*)(wbuf + n * 128 + ((ks * 64 + lg * 16) ^ ((n & 7) << 4)));
        acc2[nf] = MFMA16(a, b, acc2[nf]);
      }
    }
  }

  // ---- epilogue: +b2, relu, fp32 dot W3, +b3, sigmoid, write P ----
  #pragma unroll
  for (int r = 0; r < 4; ++r) {
    float sum = 0.f;
    #pragma unroll
    for (int nf = 0; nf < 16; ++nf) {
      float h2 = acc2[nf][r] + b2v[nf];
      h2 = h2 > 0.f ? h2 : 0.f;
      sum += h2 * w3v[nf];
    }
    sum += __shfl_xor(sum, 1);
    sum += __shfl_xor(sum, 2);
    sum += __shfl_xor(sum, 4);
    sum += __shfl_xor(sum, 8);
    if (lr == 0) {
      float logit = sum + b3v;
      float prob = 1.f / (1.f + expf(-logit));
      int pr = wid * 16 + lg * 4 + r;
      int oi = bi * 8 + (pr >> 3), oj = bj * 8 + (pr & 7);
      out[oi * NN + oj] = prob;
    }
  }
}

// ---------------- symmetrize in-place: out = 0.5*(P + P^T), zero diag ----------------
__global__ void sym_kernel(float* __restrict__ out) {
  int idx = blockIdx.x * 256 + threadIdx.x;
  if (idx >= NN * NN) return;
  int i = idx / NN, j = idx % NN;
  if (i < j) {
    float a = out[i * NN + j], b = out[j * NN + i];
    float v = 0.5f * (a + b);
    out[i * NN + j] = v;
    out[j * NN + i] = v;
  } else if (i == j) {
    out[idx] = 0.f;
  }
}

extern "C" void kernel_launch(void* const* d_in, const int* in_sizes, int n_in,
                              void* d_out, int out_size, void* d_ws, size_t ws_size,
                              hipStream_t stream) {
  const float* z   = (const float*)d_in[0];
  const float* lp  = (const float*)d_in[1];
  const float* hom = (const float*)d_in[2];
  const float* W1  = (const float*)d_in[3];
  const float* b1  = (const float*)d_in[4];
  const float* W2  = (const float*)d_in[5];
  const float* b2  = (const float*)d_in[6];
  const float* W3  = (const float*)d_in[7];
  const float* b3  = (const float*)d_in[8];
  float* out = (float*)d_out;

  char* ws = (char*)d_ws;
  _Float16* Rh  = (_Float16*)(ws);                 // 768*256*2 = 393216
  _Float16* Ch  = (_Float16*)(ws + 393216);
  _Float16* R2h = (_Float16*)(ws + 786432);
  _Float16* C2h = (_Float16*)(ws + 1179648);
  _Float16* Wm  = (_Float16*)(ws + 1572864);       // 256*64*2 = 32768
  _Float16* W2t = (_Float16*)(ws + 1605632);       // 256*256*2 = 131072 -> end 1736704

  prep_rc<<<768, 256, 0, stream>>>(z, lp, hom, W1, b1, Rh, Ch, R2h, C2h);
  prep_w<<<320, 256, 0, stream>>>(W1, W2, Wm, W2t);
  fused_mlp<<<dim3(96, 96), 256, 0, stream>>>(z, Rh, Ch, R2h, C2h, Wm, W2t, b2, W3, b3, out);
  sym_kernel<<<2304, 256, 0, stream>>>(out);
}